// Round 7
// baseline (307.201 us; speedup 1.0000x reference)
//
#include <hip/hip_runtime.h>
#include <hip/hip_bf16.h>
#include <math.h>

// Problem constants (B=2, H=12, S=2048, D=64, hash_code_len=8)
#define NB 2
#define NH 12
#define NS 2048
#define ND 64
#define NBH (NB * NH)
#define TILE_USHORT 4096        // one 64x64 bf16 tile image = 8 KB
#define QK_TILE_BLOCKS 1536     // prep: one block per 64-row tile, Q(768) + K(768)
#define V_BLOCKS (NBH * 32)     // 768

typedef __attribute__((ext_vector_type(8))) short short8;   // MFMA A/B frag
typedef __attribute__((ext_vector_type(4))) float floatx4;  // MFMA C/D frag
typedef __attribute__((ext_vector_type(2))) float float2v;  // packed f32 pair

__device__ __forceinline__ unsigned short f32_to_bf16_rne(float f) {
  unsigned int u = __float_as_uint(f);
  u += 0x7fffu + ((u >> 16) & 1u);
  return (unsigned short)(u >> 16);
}

// biased-for-RNE bf16 bits left in the HIGH half of a u32
__device__ __forceinline__ unsigned int bf16rne_bits(float f) {
  unsigned int u = __float_as_uint(f);
  return u + 0x7fffu + ((u >> 16) & 1u);
}

// pack two f32 -> two RNE bf16 in ONE v_perm_b32 (lo -> low half).
__device__ __forceinline__ unsigned int pack2_bf16_rne(float lo, float hi) {
  return __builtin_amdgcn_perm(bf16rne_bits(hi), bf16rne_bits(lo), 0x07060302);
}

// pack two f32 -> two bf16 (truncate) in ONE v_perm_b32 (lo -> low half).
__device__ __forceinline__ unsigned int pack_bf16_trunc(float lo, float hi) {
  return __builtin_amdgcn_perm(__float_as_uint(hi), __float_as_uint(lo), 0x07060302);
}

__device__ __forceinline__ float2v mk2(float x) { return (float2v){x, x}; }
__device__ __forceinline__ float2v max2(float2v a, float2v b) {
  return (float2v){fmaxf(a[0], b[0]), fmaxf(a[1], b[1])};
}
__device__ __forceinline__ float2v abs2(float2v a) {
  return (float2v){fabsf(a[0]), fabsf(a[1])};
}

// exact-ish fallback: 1 - acos(d)/pi via A&S 4.4.45 (valid on full [-1,1])
__device__ __forceinline__ float yoso_f_exact(float d) {
  const float c0 = 0.49996030f;
  const float c1 = -0.06751822f;
  const float c2 = 0.02363774f;
  const float c3 = -0.00596174f;
  float a = fminf(fabsf(d), 1.0f);
  float p = fmaf(fmaf(fmaf(c3, a, c2), a, c1), a, c0);
  float u = sqrtf(1.0f - a) * p;
  return (d >= 0.0f) ? (1.0f - u) : u;
}

// async global->LDS, 16B per lane (wave-uniform LDS base + lane*16 dest)
__device__ __forceinline__ void gload_lds16(const unsigned short* src,
                                            unsigned short* lds_dst) {
  __builtin_amdgcn_global_load_lds(
      (const __attribute__((address_space(1))) unsigned int*)(const void*)src,
      (__attribute__((address_space(3))) unsigned int*)(void*)lds_dst,
      16, 0, 0);
}

// ---------------------------------------------------------------------------
// Fragment-order tile images (per 64x64 bf16 tile, 8 KB):
//   frag_id in [0,8): 1 KB each; within a frag: lane*16B + j*2B.
// Q/K (rows n = q|t, cols k = d):
//   frag_id = (d>>5)*4 + (n>>4); lane = ((d>>3)&3)*16 + (n&15); j = d&7.
// V (MFMA#2 A-operand, k-positions permuted to match register-resident W^T):
//   frag_id = (t>>5)*4 + (d>>4); lane = ((t>>2)&3)*16 + (d&15);
//   j = ((t>>4)&1)*4 + (t&3).  Key mask folded in: stores m_t * V[t][d].
// ---------------------------------------------------------------------------
__global__ __launch_bounds__(256) void prep_all(
    const float* __restrict__ Q, const float* __restrict__ K,
    const float* __restrict__ V, const float* __restrict__ mask,
    unsigned short* __restrict__ qimg, unsigned short* __restrict__ kimg,
    unsigned short* __restrict__ vimg) {
  int blk = blockIdx.x;
  if (blk < QK_TILE_BLOCKS) {
    const float* src = Q;
    unsigned short* dst = qimg;
    if (blk >= 768) { src = K; dst = kimg; blk -= 768; }
    int ti  = blk;                 // tile index = bh*32 + kt, 0..767
    int tid = threadIdx.x;
    int w   = tid >> 6;            // 16-row group (frag row block)
    int l   = tid & 63;
    int nl  = l & 15;              // row within group
    int dq  = l >> 4;              // d-octet selector (0..3)

    const float* row = src + ((size_t)ti * 64 + w * 16 + nl) * ND + dq * 8;
    float4 a0 = *(const float4*)(row);
    float4 a1 = *(const float4*)(row + 4);
    float4 b0 = *(const float4*)(row + 32);
    float4 b1 = *(const float4*)(row + 36);

    float ss = a0.x*a0.x + a0.y*a0.y + a0.z*a0.z + a0.w*a0.w
             + a1.x*a1.x + a1.y*a1.y + a1.z*a1.z + a1.w*a1.w
             + b0.x*b0.x + b0.y*b0.y + b0.z*b0.z + b0.w*b0.w
             + b1.x*b1.x + b1.y*b1.y + b1.z*b1.z + b1.w*b1.w;
    ss += __shfl_xor(ss, 16, 64);   // reduce across dq
    ss += __shfl_xor(ss, 32, 64);
    float rn = 1.0f / fmaxf(sqrtf(ss), 1e-12f);

    uint4 o0, o1;   // d5=0 / d5=1 octet pairs (j = 0..7)
    o0.x = pack2_bf16_rne(a0.x * rn, a0.y * rn);
    o0.y = pack2_bf16_rne(a0.z * rn, a0.w * rn);
    o0.z = pack2_bf16_rne(a1.x * rn, a1.y * rn);
    o0.w = pack2_bf16_rne(a1.z * rn, a1.w * rn);
    o1.x = pack2_bf16_rne(b0.x * rn, b0.y * rn);
    o1.y = pack2_bf16_rne(b0.z * rn, b0.w * rn);
    o1.z = pack2_bf16_rne(b1.x * rn, b1.y * rn);
    o1.w = pack2_bf16_rne(b1.z * rn, b1.w * rn);

    unsigned short* op = dst + (size_t)ti * TILE_USHORT + w * 512 + l * 8;
    *(uint4*)(op)            = o0;   // frag w     (d>>5 = 0)
    *(uint4*)(op + 4 * 512)  = o1;   // frag 4 + w (d>>5 = 1)
  } else {
    int vb = blk - QK_TILE_BLOCKS;
    int bh = vb >> 5, kt = vb & 31, t0 = kt * 64;
    int b  = bh / NH;
    __shared__ float sT[64][65];   // [d][t], mask folded in
    int tid = threadIdx.x;
    int tr = tid >> 2;             // t within tile
    int dc = (tid & 3) * 16;       // d start
    float m = mask[b * NS + t0 + tr];
    const float* vp = V + ((size_t)bh * NS + t0 + tr) * ND + dc;
    #pragma unroll
    for (int jj = 0; jj < 16; jj += 4) {
      float4 v = *(const float4*)(vp + jj);
      sT[dc + jj + 0][tr] = v.x * m;
      sT[dc + jj + 1][tr] = v.y * m;
      sT[dc + jj + 2][tr] = v.z * m;
      sT[dc + jj + 3][tr] = v.w * m;
    }
    __syncthreads();
    int dr = tid >> 2;             // d row, 0..63
    unsigned short* op = vimg + (size_t)(bh * 32 + kt) * TILE_USHORT;
    #pragma unroll
    for (int g = 0; g < 2; ++g) {
      int combo = (tid & 3) * 2 + g;   // 0..7
      int kk2 = combo >> 2;            // t>>5
      int qd  = combo & 3;             // (t>>2)&3
      uint4 u;
      int tb = kk2 * 32 + qd * 4;
      u.x = (unsigned int)f32_to_bf16_rne(sT[dr][tb + 0]) |
            ((unsigned int)f32_to_bf16_rne(sT[dr][tb + 1]) << 16);
      u.y = (unsigned int)f32_to_bf16_rne(sT[dr][tb + 2]) |
            ((unsigned int)f32_to_bf16_rne(sT[dr][tb + 3]) << 16);
      u.z = (unsigned int)f32_to_bf16_rne(sT[dr][tb + 16]) |
            ((unsigned int)f32_to_bf16_rne(sT[dr][tb + 17]) << 16);
      u.w = (unsigned int)f32_to_bf16_rne(sT[dr][tb + 18]) |
            ((unsigned int)f32_to_bf16_rne(sT[dr][tb + 19]) << 16);
      int frag = kk2 * 4 + (dr >> 4);
      int ln   = qd * 16 + (dr & 15);
      *(uint4*)(op + frag * 512 + ln * 8) = u;
    }
  }
}

// ===========================================================================
// ABLATION kernel (diagnostic, this round only). Sinked via asm; NO global
// writes; full 768 grid for realistic contention. VAR:
//  0: full replica of R5 main loop (no epilogue)     -> calibrate
//  1: no arccos-poly transform (pack raw sc)         -> isolates transform VALU
//  2: no staging/ds_read/barriers (fake K from regs) -> isolates staging subsys
//  3: no V loads (fake V from regs)                  -> isolates V L2 latency
//  4: no in-loop barriers (staging+ds kept; STALE LDS reads -> timing only)
//     -> isolates barrier convoying / drain
// ===========================================================================
template<int VAR>
__global__ __launch_bounds__(256, 3) void yoso_abl(
    const unsigned short* __restrict__ qimg, const unsigned short* __restrict__ kimg,
    const unsigned short* __restrict__ vimg) {
  int bid = blockIdx.x;
  int lid = (bid & 7) * 96 + (bid >> 3);
  int bh = lid >> 5;
  int qt = lid & 31;

  __shared__ unsigned short kbuf[4][4096];

  int tid  = threadIdx.x;
  int wv   = tid >> 6;
  int lane = tid & 63;
  int lq   = lane & 15;
  int quad = lane >> 4;
  int qs   = wv & 1;
  int kp   = wv >> 1;

  uint4 qfrag[2][2];
  {
    const unsigned short* qtile = qimg + (size_t)(bh * 32 + qt) * TILE_USHORT;
    #pragma unroll
    for (int j = 0; j < 2; ++j)
      #pragma unroll
      for (int kk = 0; kk < 2; ++kk)
        qfrag[j][kk] = *(const uint4*)(qtile + (kk * 4 + qs * 2 + j) * 512 + lane * 8);
  }

  floatx4 acc[2][4];
  #pragma unroll
  for (int j = 0; j < 2; ++j)
    #pragma unroll
    for (int fd = 0; fd < 4; ++fd) acc[j][fd] = (floatx4){0.f, 0.f, 0.f, 0.f};

  const unsigned short* kb  = kimg + (size_t)bh * 32 * TILE_USHORT;
  const unsigned short* vbI = vimg + (size_t)bh * 32 * TILE_USHORT;

  const float P0 = 0.3183098862f;
  const float P1 = 0.0530516477f;
  const float P2 = 0.0238732415f;
  const float P3 = 0.0142098402f;
  const float P4 = 0.0096701727f;
  const float P5 = 0.0071212906f;

  auto stage_pair = [&](int pb, int t0) {
    #pragma unroll
    for (int c = 0; c < 4; ++c) {
      int region = wv * 4 + c;
      int tsel   = region >> 3;
      int piece  = region & 7;
      gload_lds16(kb + (size_t)(t0 + tsel) * TILE_USHORT + piece * 512 + lane * 8,
                  &kbuf[pb + tsel][piece * 512]);
    }
  };

  if constexpr (VAR != 2) {
    stage_pair(0, 0);
    if constexpr (VAR != 4) __syncthreads();
  }

  #pragma unroll 1
  for (int r = 0; r < 16; ++r) {
    int pb = (r & 1) * 2;
    if constexpr (VAR != 2) { if (r < 15) stage_pair(2 - pb, 2 * r + 2); }

    int kt = 2 * r + kp;

    uint4 kf[2][4];
    if constexpr (VAR == 2) {
      #pragma unroll
      for (int kk = 0; kk < 2; ++kk)
        #pragma unroll
        for (int ft = 0; ft < 4; ++ft)
          kf[kk][ft] = qfrag[ft & 1][kk];
    } else {
      const unsigned short* sb = kbuf[pb + kp];
      #pragma unroll
      for (int kk = 0; kk < 2; ++kk)
        #pragma unroll
        for (int ft = 0; ft < 4; ++ft)
          kf[kk][ft] = *(const uint4*)(sb + (kk * 4 + ft) * 512 + lane * 8);
    }

    floatx4 sc[2][4];
    #pragma unroll
    for (int j = 0; j < 2; ++j)
      #pragma unroll
      for (int ft = 0; ft < 4; ++ft) sc[j][ft] = (floatx4){0.f, 0.f, 0.f, 0.f};
    #pragma unroll
    for (int kk = 0; kk < 2; ++kk) {
      #pragma unroll
      for (int j = 0; j < 2; ++j) {
        short8 bq = *(const short8*)&qfrag[j][kk];
        #pragma unroll
        for (int ft = 0; ft < 4; ++ft)
          sc[j][ft] = __builtin_amdgcn_mfma_f32_16x16x32_bf16(
              *(const short8*)&kf[kk][ft], bq, sc[j][ft], 0, 0, 0);
      }
    }

    uint4 vf[2][4];
    if constexpr (VAR == 3) {
      #pragma unroll
      for (int kk2 = 0; kk2 < 2; ++kk2)
        #pragma unroll
        for (int fd = 0; fd < 4; ++fd)
          vf[kk2][fd] = qfrag[fd & 1][kk2];
    } else {
      const unsigned short* vtile = vbI + (size_t)kt * TILE_USHORT;
      #pragma unroll
      for (int kk2 = 0; kk2 < 2; ++kk2)
        #pragma unroll
        for (int fd = 0; fd < 4; ++fd)
          vf[kk2][fd] = *(const uint4*)(vtile + (kk2 * 4 + fd) * 512 + lane * 8);
    }

    if constexpr (VAR != 1) {
      float2v mxy = mk2(0.f);
      #pragma unroll
      for (int j = 0; j < 2; ++j)
        #pragma unroll
        for (int ft = 0; ft < 4; ++ft) {
          float2v* p = (float2v*)&sc[j][ft];
          mxy = max2(mxy, max2(abs2(p[0]), abs2(p[1])));
        }
      float mx = fmaxf(mxy[0], mxy[1]);
      if (VAR != 2 && __builtin_expect(__any(mx > 0.82f), 0)) {
        #pragma unroll
        for (int j = 0; j < 2; ++j)
          #pragma unroll
          for (int ft = 0; ft < 4; ++ft)
            #pragma unroll
            for (int r2 = 0; r2 < 4; ++r2) {
              float f = yoso_f_exact(sc[j][ft][r2]);
              float f2 = f * f;
              float f4 = f2 * f2;
              sc[j][ft][r2] = f4 * f4;
            }
      } else {
        float2v c5 = mk2(P5), c4 = mk2(P4), c3 = mk2(P3), c2 = mk2(P2),
                c1 = mk2(P1), c0 = mk2(P0), hf = mk2(0.5f);
        #pragma unroll
        for (int j = 0; j < 2; ++j)
          #pragma unroll
          for (int ft = 0; ft < 4; ++ft) {
            float2v* p = (float2v*)&sc[j][ft];
            #pragma unroll
            for (int hh = 0; hh < 2; ++hh) {
              float2v d = p[hh];
              float2v y = d * d;
              float2v pp = ((((c5 * y + c4) * y + c3) * y + c2) * y + c1) * y + c0;
              float2v f = pp * d + hf;
              float2v f2 = f * f;
              float2v f4 = f2 * f2;
              p[hh] = f4 * f4;
            }
          }
      }
    }

    #pragma unroll
    for (int j = 0; j < 2; ++j) {
      #pragma unroll
      for (int kk2 = 0; kk2 < 2; ++kk2) {
        uint4 u;
        u.x = pack_bf16_trunc(sc[j][2 * kk2][0], sc[j][2 * kk2][1]);
        u.y = pack_bf16_trunc(sc[j][2 * kk2][2], sc[j][2 * kk2][3]);
        u.z = pack_bf16_trunc(sc[j][2 * kk2 + 1][0], sc[j][2 * kk2 + 1][1]);
        u.w = pack_bf16_trunc(sc[j][2 * kk2 + 1][2], sc[j][2 * kk2 + 1][3]);
        short8 bw = *(short8*)&u;
        #pragma unroll
        for (int fd = 0; fd < 4; ++fd)
          acc[j][fd] = __builtin_amdgcn_mfma_f32_16x16x32_bf16(
              *(const short8*)&vf[kk2][fd], bw, acc[j][fd], 0, 0, 0);
      }
    }

    if constexpr (VAR != 2 && VAR != 4) __syncthreads();
  }

  // kp reduction (keeps kbuf referenced; same tail for all variants), then sink.
  float* xch = (float*)&kbuf[0][0];
  __syncthreads();
  if (kp == 1) {
    #pragma unroll
    for (int j = 0; j < 2; ++j) {
      float* wr = xch + (qs * 2 + j) * 1088;
      #pragma unroll
      for (int fd = 0; fd < 4; ++fd)
        #pragma unroll
        for (int r2 = 0; r2 < 4; ++r2)
          wr[lq * 68 + fd * 16 + quad * 4 + r2] = acc[j][fd][r2];
    }
  }
  __syncthreads();
  if (kp == 0) {
    #pragma unroll
    for (int j = 0; j < 2; ++j) {
      const float* rd = xch + (qs * 2 + j) * 1088;
      #pragma unroll
      for (int fd = 0; fd < 4; ++fd)
        #pragma unroll
        for (int r2 = 0; r2 < 4; ++r2)
          acc[j][fd][r2] += rd[lq * 68 + fd * 16 + quad * 4 + r2];
    }
  }
  #pragma unroll
  for (int j = 0; j < 2; ++j)
    #pragma unroll
    for (int fd = 0; fd < 4; ++fd)
      asm volatile("" :: "v"(acc[j][fd][0]), "v"(acc[j][fd][1]),
                         "v"(acc[j][fd][2]), "v"(acc[j][fd][3]));
}

// ---------------------------------------------------------------------------
// Main (REAL), R5 structure exactly (R6 rotation reverted: it was -1.4us).
// ---------------------------------------------------------------------------
__global__ __launch_bounds__(256, 3) void yoso_main(
    const unsigned short* __restrict__ qimg, const unsigned short* __restrict__ kimg,
    const unsigned short* __restrict__ vimg, const float* __restrict__ V,
    const float* __restrict__ mask, const float* __restrict__ conv_w,
    float* __restrict__ out) {
  int bid = blockIdx.x;
  int lid = (bid & 7) * 96 + (bid >> 3);   // XCD swizzle (nwg=768=8*96)
  int bh = lid >> 5;
  int b  = bh / NH;
  int h  = bh % NH;
  int qt = lid & 31;
  int s0 = qt * 64;

  __shared__ unsigned short kbuf[4][4096];

  int tid  = threadIdx.x;
  int wv   = tid >> 6;
  int lane = tid & 63;
  int lq   = lane & 15;
  int quad = lane >> 4;
  int qs   = wv & 1;
  int kp   = wv >> 1;

  uint4 qfrag[2][2];
  {
    const unsigned short* qtile = qimg + (size_t)(bh * 32 + qt) * TILE_USHORT;
    #pragma unroll
    for (int j = 0; j < 2; ++j)
      #pragma unroll
      for (int kk = 0; kk < 2; ++kk)
        qfrag[j][kk] = *(const uint4*)(qtile + (kk * 4 + qs * 2 + j) * 512 + lane * 8);
  }

  float w0 = conv_w[h * 3 + 0], w1 = conv_w[h * 3 + 1], w2 = conv_w[h * 3 + 2];

  floatx4 acc[2][4];
  #pragma unroll
  for (int j = 0; j < 2; ++j)
    #pragma unroll
    for (int fd = 0; fd < 4; ++fd) acc[j][fd] = (floatx4){0.f, 0.f, 0.f, 0.f};

  const unsigned short* kb  = kimg + (size_t)bh * 32 * TILE_USHORT;
  const unsigned short* vbI = vimg + (size_t)bh * 32 * TILE_USHORT;

  const float P0 = 0.3183098862f;
  const float P1 = 0.0530516477f;
  const float P2 = 0.0238732415f;
  const float P3 = 0.0142098402f;
  const float P4 = 0.0096701727f;
  const float P5 = 0.0071212906f;

  auto stage_pair = [&](int pb, int t0) {
    #pragma unroll
    for (int c = 0; c < 4; ++c) {
      int region = wv * 4 + c;
      int tsel   = region >> 3;
      int piece  = region & 7;
      gload_lds16(kb + (size_t)(t0 + tsel) * TILE_USHORT + piece * 512 + lane * 8,
                  &kbuf[pb + tsel][piece * 512]);
    }
  };

  stage_pair(0, 0);
  __syncthreads();

  #pragma unroll 1
  for (int r = 0; r < 16; ++r) {
    int pb = (r & 1) * 2;
    if (r < 15) stage_pair(2 - pb, 2 * r + 2);

    int kt = 2 * r + kp;
    const unsigned short* sb = kbuf[pb + kp];

    uint4 kf[2][4];
    #pragma unroll
    for (int kk = 0; kk < 2; ++kk)
      #pragma unroll
      for (int ft = 0; ft < 4; ++ft)
        kf[kk][ft] = *(const uint4*)(sb + (kk * 4 + ft) * 512 + lane * 8);

    floatx4 sc[2][4];
    #pragma unroll
    for (int j = 0; j < 2; ++j)
      #pragma unroll
      for (int ft = 0; ft < 4; ++ft) sc[j][ft] = (floatx4){0.f, 0.f, 0.f, 0.f};
    #pragma unroll
    for (int kk = 0; kk < 2; ++kk) {
      #pragma unroll
      for (int j = 0; j < 2; ++j) {
        short8 bq = *(const short8*)&qfrag[j][kk];
        #pragma unroll
        for (int ft = 0; ft < 4; ++ft)
          sc[j][ft] = __builtin_amdgcn_mfma_f32_16x16x32_bf16(
              *(const short8*)&kf[kk][ft], bq, sc[j][ft], 0, 0, 0);
      }
    }

    const unsigned short* vtile = vbI + (size_t)kt * TILE_USHORT;
    uint4 vf[2][4];
    #pragma unroll
    for (int kk2 = 0; kk2 < 2; ++kk2)
      #pragma unroll
      for (int fd = 0; fd < 4; ++fd)
        vf[kk2][fd] = *(const uint4*)(vtile + (kk2 * 4 + fd) * 512 + lane * 8);

    {
      float2v mxy = mk2(0.f);
      #pragma unroll
      for (int j = 0; j < 2; ++j)
        #pragma unroll
        for (int ft = 0; ft < 4; ++ft) {
          float2v* p = (float2v*)&sc[j][ft];
          mxy = max2(mxy, max2(abs2(p[0]), abs2(p[1])));
        }
      float mx = fmaxf(mxy[0], mxy[1]);
      if (__builtin_expect(__any(mx > 0.82f), 0)) {
        #pragma unroll
        for (int j = 0; j < 2; ++j)
          #pragma unroll
          for (int ft = 0; ft < 4; ++ft)
            #pragma unroll
            for (int r2 = 0; r2 < 4; ++r2) {
              float f = yoso_f_exact(sc[j][ft][r2]);
              float f2 = f * f;
              float f4 = f2 * f2;
              sc[j][ft][r2] = f4 * f4;
            }
      } else {
        float2v c5 = mk2(P5), c4 = mk2(P4), c3 = mk2(P3), c2 = mk2(P2),
                c1 = mk2(P1), c0 = mk2(P0), hf = mk2(0.5f);
        #pragma unroll
        for (int j = 0; j < 2; ++j)
          #pragma unroll
          for (int ft = 0; ft < 4; ++ft) {
            float2v* p = (float2v*)&sc[j][ft];
            #pragma unroll
            for (int hh = 0; hh < 2; ++hh) {
              float2v d = p[hh];
              float2v y = d * d;
              float2v pp = ((((c5 * y + c4) * y + c3) * y + c2) * y + c1) * y + c0;
              float2v f = pp * d + hf;
              float2v f2 = f * f;
              float2v f4 = f2 * f2;
              p[hh] = f4 * f4;
            }
          }
      }
    }

    #pragma unroll
    for (int j = 0; j < 2; ++j) {
      #pragma unroll
      for (int kk2 = 0; kk2 < 2; ++kk2) {
        uint4 u;
        u.x = pack_bf16_trunc(sc[j][2 * kk2][0], sc[j][2 * kk2][1]);
        u.y = pack_bf16_trunc(sc[j][2 * kk2][2], sc[j][2 * kk2][3]);
        u.z = pack_bf16_trunc(sc[j][2 * kk2 + 1][0], sc[j][2 * kk2 + 1][1]);
        u.w = pack_bf16_trunc(sc[j][2 * kk2 + 1][2], sc[j][2 * kk2 + 1][3]);
        short8 bw = *(short8*)&u;
        #pragma unroll
        for (int fd = 0; fd < 4; ++fd)
          acc[j][fd] = __builtin_amdgcn_mfma_f32_16x16x32_bf16(
              *(const short8*)&vf[kk2][fd], bw, acc[j][fd], 0, 0, 0);
      }
    }

    __syncthreads();
  }

  float* xch = (float*)&kbuf[0][0];
  if (kp == 1) {
    #pragma unroll
    for (int j = 0; j < 2; ++j) {
      float* wr = xch + (qs * 2 + j) * 1088;
      #pragma unroll
      for (int fd = 0; fd < 4; ++fd)
        #pragma unroll
        for (int r2 = 0; r2 < 4; ++r2)
          wr[lq * 68 + fd * 16 + quad * 4 + r2] = acc[j][fd][r2];
    }
  }
  __syncthreads();
  if (kp == 0) {
    #pragma unroll
    for (int j = 0; j < 2; ++j) {
      const float* rd = xch + (qs * 2 + j) * 1088;
      #pragma unroll
      for (int fd = 0; fd < 4; ++fd)
        #pragma unroll
        for (int r2 = 0; r2 < 4; ++r2)
          acc[j][fd][r2] += rd[lq * 68 + fd * 16 + quad * 4 + r2];
    }

    #pragma unroll
    for (int j = 0; j < 2; ++j) {
      int s = s0 + qs * 32 + j * 16 + lq;
      float qm  = mask[b * NS + s];
      float qm0 = (s > 0) ? mask[b * NS + s - 1] : 0.f;
      float qm2 = (s < NS - 1) ? mask[b * NS + s + 1] : 0.f;
      float ssum = 0.f;
      #pragma unroll
      for (int fd = 0; fd < 4; ++fd)
        #pragma unroll
        for (int r2 = 0; r2 < 4; ++r2) {
          float x = acc[j][fd][r2] * qm;
          acc[j][fd][r2] = x;
          ssum += x * x;
        }
      ssum += __shfl_xor(ssum, 16, 64);
      ssum += __shfl_xor(ssum, 32, 64);
      float rn = 1.0f / fmaxf(sqrtf(ssum), 1e-12f);

      const float* vfull = V + ((size_t)bh * NS + s) * ND;
      #pragma unroll
      for (int fd = 0; fd < 4; ++fd) {
        int d = fd * 16 + quad * 4;
        float4 vc1 = *(const float4*)(vfull + d);
        float4 cv;
        cv.x = w1 * vc1.x * qm; cv.y = w1 * vc1.y * qm;
        cv.z = w1 * vc1.z * qm; cv.w = w1 * vc1.w * qm;
        if (s > 0) {
          float4 vc0 = *(const float4*)(vfull - ND + d);
          cv.x += w0 * vc0.x * qm0; cv.y += w0 * vc0.y * qm0;
          cv.z += w0 * vc0.z * qm0; cv.w += w0 * vc0.w * qm0;
        }
        if (s < NS - 1) {
          float4 vc2 = *(const float4*)(vfull + ND + d);
          cv.x += w2 * vc2.x * qm2; cv.y += w2 * vc2.y * qm2;
          cv.z += w2 * vc2.z * qm2; cv.w += w2 * vc2.w * qm2;
        }
        float4 o;
        o.x = acc[j][fd][0] * rn + cv.x;
        o.y = acc[j][fd][1] * rn + cv.y;
        o.z = acc[j][fd][2] * rn + cv.z;
        o.w = acc[j][fd][3] * rn + cv.w;
        *(float4*)(out + ((size_t)bh * NS + s) * ND + d) = o;
      }
    }
  }
}

// ---------------------------------------------------------------------------
extern "C" void kernel_launch(void* const* d_in, const int* in_sizes, int n_in,
                              void* d_out, int out_size, void* d_ws, size_t ws_size,
                              hipStream_t stream) {
  const float* Q      = (const float*)d_in[0];
  const float* K      = (const float*)d_in[1];
  const float* V      = (const float*)d_in[2];
  const float* mask   = (const float*)d_in[3];
  const float* conv_w = (const float*)d_in[4];
  float* out = (float*)d_out;

  const size_t seg = (size_t)NBH * NS * ND * sizeof(unsigned short);  // 6.29 MB
  unsigned short* qimg = (unsigned short*)d_ws;
  unsigned short* kimg = (unsigned short*)((char*)d_ws + seg);
  unsigned short* vimg = (unsigned short*)((char*)d_ws + 2 * seg);

  prep_all<<<QK_TILE_BLOCKS + V_BLOCKS, 256, 0, stream>>>(Q, K, V, mask, qimg, kimg, vimg);
  // --- diagnostic ablation dispatches (no global writes; timing via rocprof) ---
  yoso_abl<0><<<NBH * 32, 256, 0, stream>>>(qimg, kimg, vimg);
  yoso_abl<1><<<NBH * 32, 256, 0, stream>>>(qimg, kimg, vimg);
  yoso_abl<2><<<NBH * 32, 256, 0, stream>>>(qimg, kimg, vimg);
  yoso_abl<3><<<NBH * 32, 256, 0, stream>>>(qimg, kimg, vimg);
  yoso_abl<4><<<NBH * 32, 256, 0, stream>>>(qimg, kimg, vimg);
  // --- real kernel (authoritative output) ---
  yoso_main<<<NBH * 32, 256, 0, stream>>>(qimg, kimg, vimg, V, mask, conv_w, out);
}

// Round 8
// 280.054 us; speedup vs baseline: 1.0969x; 1.0969x over previous
//
#include <hip/hip_runtime.h>
#include <hip/hip_bf16.h>
#include <math.h>

// Problem constants (B=2, H=12, S=2048, D=64, hash_code_len=8)
#define NB 2
#define NH 12
#define NS 2048
#define ND 64
#define NBH (NB * NH)
#define TILE_USHORT 4096        // one 64x64 bf16 tile image = 8 KB
#define QK_TILE_BLOCKS 1536     // prep: one block per 64-row tile, Q(768) + K(768)
#define V_BLOCKS (NBH * 32)     // 768

typedef __attribute__((ext_vector_type(8))) short short8;   // MFMA A/B frag
typedef __attribute__((ext_vector_type(4))) float floatx4;  // MFMA C/D frag
typedef __attribute__((ext_vector_type(2))) float float2v;  // packed f32 pair

__device__ __forceinline__ unsigned short f32_to_bf16_rne(float f) {
  unsigned int u = __float_as_uint(f);
  u += 0x7fffu + ((u >> 16) & 1u);
  return (unsigned short)(u >> 16);
}

// biased-for-RNE bf16 bits left in the HIGH half of a u32
__device__ __forceinline__ unsigned int bf16rne_bits(float f) {
  unsigned int u = __float_as_uint(f);
  return u + 0x7fffu + ((u >> 16) & 1u);
}

// pack two f32 -> two RNE bf16 in ONE v_perm_b32 (lo -> low half).
__device__ __forceinline__ unsigned int pack2_bf16_rne(float lo, float hi) {
  return __builtin_amdgcn_perm(bf16rne_bits(hi), bf16rne_bits(lo), 0x07060302);
}

// pack two f32 -> two bf16 (truncate) in ONE v_perm_b32 (lo -> low half).
__device__ __forceinline__ unsigned int pack_bf16_trunc(float lo, float hi) {
  return __builtin_amdgcn_perm(__float_as_uint(hi), __float_as_uint(lo), 0x07060302);
}

__device__ __forceinline__ float2v mk2(float x) { return (float2v){x, x}; }
__device__ __forceinline__ float2v max2(float2v a, float2v b) {
  return (float2v){fmaxf(a[0], b[0]), fmaxf(a[1], b[1])};
}
__device__ __forceinline__ float2v abs2(float2v a) {
  return (float2v){fabsf(a[0]), fabsf(a[1])};
}

// exact-ish fallback: 1 - acos(d)/pi via A&S 4.4.45 (valid on full [-1,1])
__device__ __forceinline__ float yoso_f_exact(float d) {
  const float c0 = 0.49996030f;
  const float c1 = -0.06751822f;
  const float c2 = 0.02363774f;
  const float c3 = -0.00596174f;
  float a = fminf(fabsf(d), 1.0f);
  float p = fmaf(fmaf(fmaf(c3, a, c2), a, c1), a, c0);
  float u = sqrtf(1.0f - a) * p;
  return (d >= 0.0f) ? (1.0f - u) : u;
}

// async global->LDS, 16B per lane (wave-uniform LDS base + lane*16 dest)
__device__ __forceinline__ void gload_lds16(const unsigned short* src,
                                            unsigned short* lds_dst) {
  __builtin_amdgcn_global_load_lds(
      (const __attribute__((address_space(1))) unsigned int*)(const void*)src,
      (__attribute__((address_space(3))) unsigned int*)(void*)lds_dst,
      16, 0, 0);
}

// ---------------------------------------------------------------------------
// Fragment-order tile images (per 64x64 bf16 tile, 8 KB):
//   frag_id in [0,8): 1 KB each; within a frag: lane*16B + j*2B.
// Q/K (rows n = q|t, cols k = d):
//   frag_id = (d>>5)*4 + (n>>4); lane = ((d>>3)&3)*16 + (n&15); j = d&7.
// V (MFMA#2 A-operand, k-positions permuted to match register-resident W^T):
//   frag_id = (t>>5)*4 + (d>>4); lane = ((t>>2)&3)*16 + (d&15);
//   j = ((t>>4)&1)*4 + (t&3).  Key mask folded in: stores m_t * V[t][d].
// ---------------------------------------------------------------------------
__global__ __launch_bounds__(256) void prep_all(
    const float* __restrict__ Q, const float* __restrict__ K,
    const float* __restrict__ V, const float* __restrict__ mask,
    unsigned short* __restrict__ qimg, unsigned short* __restrict__ kimg,
    unsigned short* __restrict__ vimg) {
  int blk = blockIdx.x;
  if (blk < QK_TILE_BLOCKS) {
    const float* src = Q;
    unsigned short* dst = qimg;
    if (blk >= 768) { src = K; dst = kimg; blk -= 768; }
    int ti  = blk;                 // tile index = bh*32 + kt, 0..767
    int tid = threadIdx.x;
    int w   = tid >> 6;            // 16-row group (frag row block)
    int l   = tid & 63;
    int nl  = l & 15;              // row within group
    int dq  = l >> 4;              // d-octet selector (0..3)

    const float* row = src + ((size_t)ti * 64 + w * 16 + nl) * ND + dq * 8;
    float4 a0 = *(const float4*)(row);
    float4 a1 = *(const float4*)(row + 4);
    float4 b0 = *(const float4*)(row + 32);
    float4 b1 = *(const float4*)(row + 36);

    float ss = a0.x*a0.x + a0.y*a0.y + a0.z*a0.z + a0.w*a0.w
             + a1.x*a1.x + a1.y*a1.y + a1.z*a1.z + a1.w*a1.w
             + b0.x*b0.x + b0.y*b0.y + b0.z*b0.z + b0.w*b0.w
             + b1.x*b1.x + b1.y*b1.y + b1.z*b1.z + b1.w*b1.w;
    ss += __shfl_xor(ss, 16, 64);   // reduce across dq
    ss += __shfl_xor(ss, 32, 64);
    float rn = 1.0f / fmaxf(sqrtf(ss), 1e-12f);

    uint4 o0, o1;   // d5=0 / d5=1 octet pairs (j = 0..7)
    o0.x = pack2_bf16_rne(a0.x * rn, a0.y * rn);
    o0.y = pack2_bf16_rne(a0.z * rn, a0.w * rn);
    o0.z = pack2_bf16_rne(a1.x * rn, a1.y * rn);
    o0.w = pack2_bf16_rne(a1.z * rn, a1.w * rn);
    o1.x = pack2_bf16_rne(b0.x * rn, b0.y * rn);
    o1.y = pack2_bf16_rne(b0.z * rn, b0.w * rn);
    o1.z = pack2_bf16_rne(b1.x * rn, b1.y * rn);
    o1.w = pack2_bf16_rne(b1.z * rn, b1.w * rn);

    unsigned short* op = dst + (size_t)ti * TILE_USHORT + w * 512 + l * 8;
    *(uint4*)(op)            = o0;   // frag w     (d>>5 = 0)
    *(uint4*)(op + 4 * 512)  = o1;   // frag 4 + w (d>>5 = 1)
  } else {
    int vb = blk - QK_TILE_BLOCKS;
    int bh = vb >> 5, kt = vb & 31, t0 = kt * 64;
    int b  = bh / NH;
    __shared__ float sT[64][65];   // [d][t], mask folded in
    int tid = threadIdx.x;
    int tr = tid >> 2;             // t within tile
    int dc = (tid & 3) * 16;       // d start
    float m = mask[b * NS + t0 + tr];
    const float* vp = V + ((size_t)bh * NS + t0 + tr) * ND + dc;
    #pragma unroll
    for (int jj = 0; jj < 16; jj += 4) {
      float4 v = *(const float4*)(vp + jj);
      sT[dc + jj + 0][tr] = v.x * m;
      sT[dc + jj + 1][tr] = v.y * m;
      sT[dc + jj + 2][tr] = v.z * m;
      sT[dc + jj + 3][tr] = v.w * m;
    }
    __syncthreads();
    int dr = tid >> 2;             // d row, 0..63
    unsigned short* op = vimg + (size_t)(bh * 32 + kt) * TILE_USHORT;
    #pragma unroll
    for (int g = 0; g < 2; ++g) {
      int combo = (tid & 3) * 2 + g;   // 0..7
      int kk2 = combo >> 2;            // t>>5
      int qd  = combo & 3;             // (t>>2)&3
      uint4 u;
      int tb = kk2 * 32 + qd * 4;
      u.x = (unsigned int)f32_to_bf16_rne(sT[dr][tb + 0]) |
            ((unsigned int)f32_to_bf16_rne(sT[dr][tb + 1]) << 16);
      u.y = (unsigned int)f32_to_bf16_rne(sT[dr][tb + 2]) |
            ((unsigned int)f32_to_bf16_rne(sT[dr][tb + 3]) << 16);
      u.z = (unsigned int)f32_to_bf16_rne(sT[dr][tb + 16]) |
            ((unsigned int)f32_to_bf16_rne(sT[dr][tb + 17]) << 16);
      u.w = (unsigned int)f32_to_bf16_rne(sT[dr][tb + 18]) |
            ((unsigned int)f32_to_bf16_rne(sT[dr][tb + 19]) << 16);
      int frag = kk2 * 4 + (dr >> 4);
      int ln   = qd * 16 + (dr & 15);
      *(uint4*)(op + frag * 512 + ln * 8) = u;
    }
  }
}

// ---------------------------------------------------------------------------
// Main, R8: OCCUPANCY DOUBLING at constant traffic.
// R7 ablation: every subsystem removal saved ~proportionally (variants sum
// ~167us, all <56.4) -> issue/occupancy-bound (22% occupancy, ~2 eff.
// waves/SIMD). Fix: 512-thread blocks, 8 waves, same 64-row tile, grid 768
// -> 3 blocks x 8 waves = 24 waves/CU (75% static), launch_bounds(512,6)
// caps VGPR at 85 (R5 state was 84 with MORE per-wave state).
// Wave split: qs = wv&1 (32-row q-half, 2 slices j), kp = (wv>>1)&1 (tile
// parity), tk = wv>>2 (KEY-HALF of the tile). tk splits the k-dimension:
// per-wave V reads halve (4KB) -> global/L2 traffic CONSERVED vs R5
// (naive 8-wave split would double V traffic to ~786MB ~ 23us of L2 BW).
// Per wave per round: 4 K-ds_reads, 8 MFMA1, 16-val transform, 4 V-frag
// loads, 8 MFMA2. End: 2-step LDS reduction (tk, then kp) reusing kbuf
// (8 x 4KB slices, exact fit), then epilogue on (kp=0,tk=0) waves.
// ---------------------------------------------------------------------------
__global__ __launch_bounds__(512, 6) void yoso_main(
    const unsigned short* __restrict__ qimg, const unsigned short* __restrict__ kimg,
    const unsigned short* __restrict__ vimg, const float* __restrict__ V,
    const float* __restrict__ mask, const float* __restrict__ conv_w,
    float* __restrict__ out) {
  int bid = blockIdx.x;
  int lid = (bid & 7) * 96 + (bid >> 3);   // XCD swizzle (nwg=768=8*96)
  int bh = lid >> 5;
  int b  = bh / NH;
  int h  = bh % NH;
  int qt = lid & 31;
  int s0 = qt * 64;

  __shared__ unsigned short kbuf[4][4096];  // 4 x 8KB K-tile buffers

  int tid  = threadIdx.x;
  int wv   = tid >> 6;       // 0..7
  int lane = tid & 63;
  int lq   = lane & 15;
  int quad = lane >> 4;
  int qs   = wv & 1;         // q half (32 rows = 2 slices)
  int kp   = (wv >> 1) & 1;  // tile parity
  int tk   = wv >> 2;        // key half within tile (k-dim split)

  // Loop-invariant Q fragments: slice j covers rows s0 + qs*32 + j*16 + lq.
  uint4 qfrag[2][2];   // [j][kk]
  {
    const unsigned short* qtile = qimg + (size_t)(bh * 32 + qt) * TILE_USHORT;
    #pragma unroll
    for (int j = 0; j < 2; ++j)
      #pragma unroll
      for (int kk = 0; kk < 2; ++kk)
        qfrag[j][kk] = *(const uint4*)(qtile + (kk * 4 + qs * 2 + j) * 512 + lane * 8);
  }

  float w0 = conv_w[h * 3 + 0], w1 = conv_w[h * 3 + 1], w2 = conv_w[h * 3 + 2];

  floatx4 acc[2][4];   // [j][fd]: partial X^T (keys [tk*32,+32) of parity kp)
  #pragma unroll
  for (int j = 0; j < 2; ++j)
    #pragma unroll
    for (int fd = 0; fd < 4; ++fd) acc[j][fd] = (floatx4){0.f, 0.f, 0.f, 0.f};

  const unsigned short* kb  = kimg + (size_t)bh * 32 * TILE_USHORT;
  const unsigned short* vbI = vimg + (size_t)bh * 32 * TILE_USHORT;

  const float P0 = 0.3183098862f;
  const float P1 = 0.0530516477f;
  const float P2 = 0.0238732415f;
  const float P3 = 0.0142098402f;
  const float P4 = 0.0096701727f;
  const float P5 = 0.0071212906f;

  // Stage tile pair {t0, t0+1} into kbuf[pb], kbuf[pb+1]: 16 x 1KB pieces
  // split across 8 waves x 2 gload_lds16.
  auto stage_pair = [&](int pb, int t0) {
    #pragma unroll
    for (int c = 0; c < 2; ++c) {
      int region = wv * 2 + c;       // 0..15
      int tsel   = region >> 3;
      int piece  = region & 7;
      gload_lds16(kb + (size_t)(t0 + tsel) * TILE_USHORT + piece * 512 + lane * 8,
                  &kbuf[pb + tsel][piece * 512]);
    }
  };

  stage_pair(0, 0);
  __syncthreads();

  #pragma unroll 1
  for (int r = 0; r < 16; ++r) {
    int pb = (r & 1) * 2;
    if (r < 15) stage_pair(2 - pb, 2 * r + 2);

    int kt = 2 * r + kp;
    const unsigned short* sb = kbuf[pb + kp];

    // --- K fragments for OUR key half: global ft = tk*2 + fl ---
    uint4 kf[2][2];   // [kk][fl]
    #pragma unroll
    for (int kk = 0; kk < 2; ++kk)
      #pragma unroll
      for (int fl = 0; fl < 2; ++fl)
        kf[kk][fl] = *(const uint4*)(sb + (kk * 4 + tk * 2 + fl) * 512 + lane * 8);

    floatx4 sc[2][2];   // [j][fl]: keys t = (tk*2+fl)*16 + quad*4 + r
    #pragma unroll
    for (int j = 0; j < 2; ++j)
      #pragma unroll
      for (int fl = 0; fl < 2; ++fl) sc[j][fl] = (floatx4){0.f, 0.f, 0.f, 0.f};
    #pragma unroll
    for (int kk = 0; kk < 2; ++kk) {
      #pragma unroll
      for (int j = 0; j < 2; ++j) {
        short8 bq = *(const short8*)&qfrag[j][kk];
        #pragma unroll
        for (int fl = 0; fl < 2; ++fl)
          sc[j][fl] = __builtin_amdgcn_mfma_f32_16x16x32_bf16(
              *(const short8*)&kf[kk][fl], bq, sc[j][fl], 0, 0, 0);
      }
    }

    // --- V fragments for OUR key half (kk2 = tk): 4KB direct from L2 ---
    const unsigned short* vtile = vbI + (size_t)kt * TILE_USHORT;
    uint4 vf[4];
    #pragma unroll
    for (int fd = 0; fd < 4; ++fd)
      vf[fd] = *(const uint4*)(vtile + (tk * 4 + fd) * 512 + lane * 8);

    // --- transform in place: sc := W = (1/2 + asin(d)/pi)^8 ---
    {
      float2v mxy = mk2(0.f);
      #pragma unroll
      for (int j = 0; j < 2; ++j)
        #pragma unroll
        for (int fl = 0; fl < 2; ++fl) {
          float2v* p = (float2v*)&sc[j][fl];
          mxy = max2(mxy, max2(abs2(p[0]), abs2(p[1])));
        }
      float mx = fmaxf(mxy[0], mxy[1]);
      if (__builtin_expect(__any(mx > 0.82f), 0)) {
        #pragma unroll
        for (int j = 0; j < 2; ++j)
          #pragma unroll
          for (int fl = 0; fl < 2; ++fl)
            #pragma unroll
            for (int r2 = 0; r2 < 4; ++r2) {
              float f = yoso_f_exact(sc[j][fl][r2]);
              float f2 = f * f;
              float f4 = f2 * f2;
              sc[j][fl][r2] = f4 * f4;
            }
      } else {
        float2v c5 = mk2(P5), c4 = mk2(P4), c3 = mk2(P3), c2 = mk2(P2),
                c1 = mk2(P1), c0 = mk2(P0), hf = mk2(0.5f);
        #pragma unroll
        for (int j = 0; j < 2; ++j)
          #pragma unroll
          for (int fl = 0; fl < 2; ++fl) {
            float2v* p = (float2v*)&sc[j][fl];
            #pragma unroll
            for (int hh = 0; hh < 2; ++hh) {
              float2v d = p[hh];
              float2v y = d * d;
              float2v pp = ((((c5 * y + c4) * y + c3) * y + c2) * y + c1) * y + c0;
              float2v f = pp * d + hf;
              float2v f2 = f * f;
              float2v f4 = f2 * f2;
              p[hh] = f4 * f4;
            }
          }
      }
    }

    // --- MFMA#2: partial X^T += Vm^T · W^T (our kk2 = tk only) ---
    #pragma unroll
    for (int j = 0; j < 2; ++j) {
      uint4 u;
      u.x = pack_bf16_trunc(sc[j][0][0], sc[j][0][1]);
      u.y = pack_bf16_trunc(sc[j][0][2], sc[j][0][3]);
      u.z = pack_bf16_trunc(sc[j][1][0], sc[j][1][1]);
      u.w = pack_bf16_trunc(sc[j][1][2], sc[j][1][3]);
      short8 bw = *(short8*)&u;
      #pragma unroll
      for (int fd = 0; fd < 4; ++fd)
        acc[j][fd] = __builtin_amdgcn_mfma_f32_16x16x32_bf16(
            *(const short8*)&vf[fd], bw, acc[j][fd], 0, 0, 0);
    }

    __syncthreads();
  }

  // --- 2-step reduction over (tk, kp) via kbuf (8 x 4KB slices) ---
  // Slice layout: xch[slice*1024 + col*16 + lq], col = fd*16 + quad*4 + r2
  // (transposed: 4-way worst-case bank aliasing, one-time cost).
  float* xch = (float*)&kbuf[0][0];
  // step 1: tk=1 exports; tk=0 adds.
  if (tk == 1) {
    #pragma unroll
    for (int j = 0; j < 2; ++j) {
      float* wr = xch + (((qs * 2 + kp) * 2 + j) << 10);
      #pragma unroll
      for (int fd = 0; fd < 4; ++fd)
        #pragma unroll
        for (int r2 = 0; r2 < 4; ++r2)
          wr[(fd * 16 + quad * 4 + r2) * 16 + lq] = acc[j][fd][r2];
    }
  }
  __syncthreads();
  if (tk == 0) {
    #pragma unroll
    for (int j = 0; j < 2; ++j) {
      const float* rd = xch + (((qs * 2 + kp) * 2 + j) << 10);
      #pragma unroll
      for (int fd = 0; fd < 4; ++fd)
        #pragma unroll
        for (int r2 = 0; r2 < 4; ++r2)
          acc[j][fd][r2] += rd[(fd * 16 + quad * 4 + r2) * 16 + lq];
    }
  }
  __syncthreads();
  // step 2: (tk=0,kp=1) exports; (tk=0,kp=0) adds + epilogue.
  if (tk == 0 && kp == 1) {
    #pragma unroll
    for (int j = 0; j < 2; ++j) {
      float* wr = xch + (((qs * 2) + j) << 10);
      #pragma unroll
      for (int fd = 0; fd < 4; ++fd)
        #pragma unroll
        for (int r2 = 0; r2 < 4; ++r2)
          wr[(fd * 16 + quad * 4 + r2) * 16 + lq] = acc[j][fd][r2];
    }
  }
  __syncthreads();
  if (tk == 0 && kp == 0) {
    #pragma unroll
    for (int j = 0; j < 2; ++j) {
      const float* rd = xch + (((qs * 2) + j) << 10);
      #pragma unroll
      for (int fd = 0; fd < 4; ++fd)
        #pragma unroll
        for (int r2 = 0; r2 < 4; ++r2)
          acc[j][fd][r2] += rd[(fd * 16 + quad * 4 + r2) * 16 + lq];
    }

    // --- epilogue: slices j -> q = s0 + qs*32 + j*16 + lq ---
    #pragma unroll
    for (int j = 0; j < 2; ++j) {
      int s = s0 + qs * 32 + j * 16 + lq;
      float qm  = mask[b * NS + s];
      float qm0 = (s > 0) ? mask[b * NS + s - 1] : 0.f;
      float qm2 = (s < NS - 1) ? mask[b * NS + s + 1] : 0.f;
      float ssum = 0.f;
      #pragma unroll
      for (int fd = 0; fd < 4; ++fd)
        #pragma unroll
        for (int r2 = 0; r2 < 4; ++r2) {
          float x = acc[j][fd][r2] * qm;
          acc[j][fd][r2] = x;
          ssum += x * x;
        }
      ssum += __shfl_xor(ssum, 16, 64);
      ssum += __shfl_xor(ssum, 32, 64);
      float rn = 1.0f / fmaxf(sqrtf(ssum), 1e-12f);

      const float* vfull = V + ((size_t)bh * NS + s) * ND;
      #pragma unroll
      for (int fd = 0; fd < 4; ++fd) {
        int d = fd * 16 + quad * 4;
        float4 vc1 = *(const float4*)(vfull + d);
        float4 cv;
        cv.x = w1 * vc1.x * qm; cv.y = w1 * vc1.y * qm;
        cv.z = w1 * vc1.z * qm; cv.w = w1 * vc1.w * qm;
        if (s > 0) {
          float4 vc0 = *(const float4*)(vfull - ND + d);
          cv.x += w0 * vc0.x * qm0; cv.y += w0 * vc0.y * qm0;
          cv.z += w0 * vc0.z * qm0; cv.w += w0 * vc0.w * qm0;
        }
        if (s < NS - 1) {
          float4 vc2 = *(const float4*)(vfull + ND + d);
          cv.x += w2 * vc2.x * qm2; cv.y += w2 * vc2.y * qm2;
          cv.z += w2 * vc2.z * qm2; cv.w += w2 * vc2.w * qm2;
        }
        float4 o;
        o.x = acc[j][fd][0] * rn + cv.x;
        o.y = acc[j][fd][1] * rn + cv.y;
        o.z = acc[j][fd][2] * rn + cv.z;
        o.w = acc[j][fd][3] * rn + cv.w;
        *(float4*)(out + ((size_t)bh * NS + s) * ND + d) = o;
      }
    }
  }
}

// ---------------------------------------------------------------------------
extern "C" void kernel_launch(void* const* d_in, const int* in_sizes, int n_in,
                              void* d_out, int out_size, void* d_ws, size_t ws_size,
                              hipStream_t stream) {
  const float* Q      = (const float*)d_in[0];
  const float* K      = (const float*)d_in[1];
  const float* V      = (const float*)d_in[2];
  const float* mask   = (const float*)d_in[3];
  const float* conv_w = (const float*)d_in[4];
  float* out = (float*)d_out;

  const size_t seg = (size_t)NBH * NS * ND * sizeof(unsigned short);  // 6.29 MB
  unsigned short* qimg = (unsigned short*)d_ws;
  unsigned short* kimg = (unsigned short*)((char*)d_ws + seg);
  unsigned short* vimg = (unsigned short*)((char*)d_ws + 2 * seg);

  prep_all<<<QK_TILE_BLOCKS + V_BLOCKS, 256, 0, stream>>>(Q, K, V, mask, qimg, kimg, vimg);
  yoso_main<<<NBH * 32, 512, 0, stream>>>(qimg, kimg, vimg, V, mask, conv_w, out);
}

// Round 9
// 136.577 us; speedup vs baseline: 2.2493x; 2.0505x over previous
//
#include <hip/hip_runtime.h>
#include <hip/hip_bf16.h>
#include <math.h>

// Problem constants (B=2, H=12, S=2048, D=64, hash_code_len=8)
#define NB 2
#define NH 12
#define NS 2048
#define ND 64
#define NBH (NB * NH)
#define TILE_USHORT 4096        // one 64x64 bf16 tile image = 8 KB
#define QK_TILE_BLOCKS 1536     // prep: one block per 64-row tile, Q(768) + K(768)
#define V_BLOCKS (NBH * 32)     // 768

typedef __attribute__((ext_vector_type(8))) short short8;   // MFMA A/B frag
typedef __attribute__((ext_vector_type(4))) float floatx4;  // MFMA C/D frag
typedef __attribute__((ext_vector_type(2))) float float2v;  // packed f32 pair

__device__ __forceinline__ unsigned short f32_to_bf16_rne(float f) {
  unsigned int u = __float_as_uint(f);
  u += 0x7fffu + ((u >> 16) & 1u);
  return (unsigned short)(u >> 16);
}

// biased-for-RNE bf16 bits left in the HIGH half of a u32
__device__ __forceinline__ unsigned int bf16rne_bits(float f) {
  unsigned int u = __float_as_uint(f);
  return u + 0x7fffu + ((u >> 16) & 1u);
}

// pack two f32 -> two RNE bf16 in ONE v_perm_b32 (lo -> low half).
__device__ __forceinline__ unsigned int pack2_bf16_rne(float lo, float hi) {
  return __builtin_amdgcn_perm(bf16rne_bits(hi), bf16rne_bits(lo), 0x07060302);
}

// pack two f32 -> two bf16 (truncate) in ONE v_perm_b32 (lo -> low half).
__device__ __forceinline__ unsigned int pack_bf16_trunc(float lo, float hi) {
  return __builtin_amdgcn_perm(__float_as_uint(hi), __float_as_uint(lo), 0x07060302);
}

__device__ __forceinline__ float2v mk2(float x) { return (float2v){x, x}; }
__device__ __forceinline__ float2v max2(float2v a, float2v b) {
  return (float2v){fmaxf(a[0], b[0]), fmaxf(a[1], b[1])};
}
__device__ __forceinline__ float2v abs2(float2v a) {
  return (float2v){fabsf(a[0]), fabsf(a[1])};
}

// exact-ish fallback: 1 - acos(d)/pi via A&S 4.4.45 (valid on full [-1,1])
__device__ __forceinline__ float yoso_f_exact(float d) {
  const float c0 = 0.49996030f;
  const float c1 = -0.06751822f;
  const float c2 = 0.02363774f;
  const float c3 = -0.00596174f;
  float a = fminf(fabsf(d), 1.0f);
  float p = fmaf(fmaf(fmaf(c3, a, c2), a, c1), a, c0);
  float u = sqrtf(1.0f - a) * p;
  return (d >= 0.0f) ? (1.0f - u) : u;
}

// async global->LDS, 16B per lane (wave-uniform LDS base + lane*16 dest)
__device__ __forceinline__ void gload_lds16(const unsigned short* src,
                                            unsigned short* lds_dst) {
  __builtin_amdgcn_global_load_lds(
      (const __attribute__((address_space(1))) unsigned int*)(const void*)src,
      (__attribute__((address_space(3))) unsigned int*)(void*)lds_dst,
      16, 0, 0);
}

// ---------------------------------------------------------------------------
// Fragment-order tile images (per 64x64 bf16 tile, 8 KB):
//   frag_id in [0,8): 1 KB each; within a frag: lane*16B + j*2B.
// Q/K (rows n = q|t, cols k = d):
//   frag_id = (d>>5)*4 + (n>>4); lane = ((d>>3)&3)*16 + (n&15); j = d&7.
// V (MFMA#2 A-operand, k-positions permuted to match register-resident W^T):
//   frag_id = (t>>5)*4 + (d>>4); lane = ((t>>2)&3)*16 + (d&15);
//   j = ((t>>4)&1)*4 + (t&3).  Key mask folded in: stores m_t * V[t][d].
// ---------------------------------------------------------------------------
__global__ __launch_bounds__(256) void prep_all(
    const float* __restrict__ Q, const float* __restrict__ K,
    const float* __restrict__ V, const float* __restrict__ mask,
    unsigned short* __restrict__ qimg, unsigned short* __restrict__ kimg,
    unsigned short* __restrict__ vimg) {
  int blk = blockIdx.x;
  if (blk < QK_TILE_BLOCKS) {
    const float* src = Q;
    unsigned short* dst = qimg;
    if (blk >= 768) { src = K; dst = kimg; blk -= 768; }
    int ti  = blk;                 // tile index = bh*32 + kt, 0..767
    int tid = threadIdx.x;
    int w   = tid >> 6;            // 16-row group (frag row block)
    int l   = tid & 63;
    int nl  = l & 15;              // row within group
    int dq  = l >> 4;              // d-octet selector (0..3)

    const float* row = src + ((size_t)ti * 64 + w * 16 + nl) * ND + dq * 8;
    float4 a0 = *(const float4*)(row);
    float4 a1 = *(const float4*)(row + 4);
    float4 b0 = *(const float4*)(row + 32);
    float4 b1 = *(const float4*)(row + 36);

    float ss = a0.x*a0.x + a0.y*a0.y + a0.z*a0.z + a0.w*a0.w
             + a1.x*a1.x + a1.y*a1.y + a1.z*a1.z + a1.w*a1.w
             + b0.x*b0.x + b0.y*b0.y + b0.z*b0.z + b0.w*b0.w
             + b1.x*b1.x + b1.y*b1.y + b1.z*b1.z + b1.w*b1.w;
    ss += __shfl_xor(ss, 16, 64);   // reduce across dq
    ss += __shfl_xor(ss, 32, 64);
    float rn = 1.0f / fmaxf(sqrtf(ss), 1e-12f);

    uint4 o0, o1;   // d5=0 / d5=1 octet pairs (j = 0..7)
    o0.x = pack2_bf16_rne(a0.x * rn, a0.y * rn);
    o0.y = pack2_bf16_rne(a0.z * rn, a0.w * rn);
    o0.z = pack2_bf16_rne(a1.x * rn, a1.y * rn);
    o0.w = pack2_bf16_rne(a1.z * rn, a1.w * rn);
    o1.x = pack2_bf16_rne(b0.x * rn, b0.y * rn);
    o1.y = pack2_bf16_rne(b0.z * rn, b0.w * rn);
    o1.z = pack2_bf16_rne(b1.x * rn, b1.y * rn);
    o1.w = pack2_bf16_rne(b1.z * rn, b1.w * rn);

    unsigned short* op = dst + (size_t)ti * TILE_USHORT + w * 512 + l * 8;
    *(uint4*)(op)            = o0;   // frag w     (d>>5 = 0)
    *(uint4*)(op + 4 * 512)  = o1;   // frag 4 + w (d>>5 = 1)
  } else {
    int vb = blk - QK_TILE_BLOCKS;
    int bh = vb >> 5, kt = vb & 31, t0 = kt * 64;
    int b  = bh / NH;
    __shared__ float sT[64][65];   // [d][t], mask folded in
    int tid = threadIdx.x;
    int tr = tid >> 2;             // t within tile
    int dc = (tid & 3) * 16;       // d start
    float m = mask[b * NS + t0 + tr];
    const float* vp = V + ((size_t)bh * NS + t0 + tr) * ND + dc;
    #pragma unroll
    for (int jj = 0; jj < 16; jj += 4) {
      float4 v = *(const float4*)(vp + jj);
      sT[dc + jj + 0][tr] = v.x * m;
      sT[dc + jj + 1][tr] = v.y * m;
      sT[dc + jj + 2][tr] = v.z * m;
      sT[dc + jj + 3][tr] = v.w * m;
    }
    __syncthreads();
    int dr = tid >> 2;             // d row, 0..63
    unsigned short* op = vimg + (size_t)(bh * 32 + kt) * TILE_USHORT;
    #pragma unroll
    for (int g = 0; g < 2; ++g) {
      int combo = (tid & 3) * 2 + g;   // 0..7
      int kk2 = combo >> 2;            // t>>5
      int qd  = combo & 3;             // (t>>2)&3
      uint4 u;
      int tb = kk2 * 32 + qd * 4;
      u.x = (unsigned int)f32_to_bf16_rne(sT[dr][tb + 0]) |
            ((unsigned int)f32_to_bf16_rne(sT[dr][tb + 1]) << 16);
      u.y = (unsigned int)f32_to_bf16_rne(sT[dr][tb + 2]) |
            ((unsigned int)f32_to_bf16_rne(sT[dr][tb + 3]) << 16);
      u.z = (unsigned int)f32_to_bf16_rne(sT[dr][tb + 16]) |
            ((unsigned int)f32_to_bf16_rne(sT[dr][tb + 17]) << 16);
      u.w = (unsigned int)f32_to_bf16_rne(sT[dr][tb + 18]) |
            ((unsigned int)f32_to_bf16_rne(sT[dr][tb + 19]) << 16);
      int frag = kk2 * 4 + (dr >> 4);
      int ln   = qd * 16 + (dr & 15);
      *(uint4*)(op + frag * 512 + ln * 8) = u;
    }
  }
}

// ---------------------------------------------------------------------------
// Main, R9: 24 waves/CU WITH state that fits the VGPR cap.
// R8 failed by spill: (qs,kp,tk) split needed ~95 live VGPRs vs (512,6)'s
// ~85 cap -> VGPR 40 + 780MB scratch traffic. New 8-wave split:
//   j  = wv&3  : q slice (16 rows) -> acc shrinks to [4] (16 regs)
//   tk = wv>>2 : key half of every tile (k-dim split)
// No kp parity: every wave walks all 32 tiles; single-tile double buffer
// (2 x 8KB LDS, stage piece wv of tile kt+1 while computing kt). Peak live
// state ~63 VGPR < 85 -> 3 blocks x 8 waves = 24 waves/CU (75% static).
// V reads: per wave 4KB/tile (its tk half) direct from L2; 8 readers ->
// ~786MB L2 (23us chip-time, affordable); HBM FETCH unchanged (L2-resident).
// End: ONE reduction step (tk) via LDS reuse, epilogue per tk=0 wave.
// Spill check next round: VGPR_Count ~64-72, WRITE_SIZE ~13.8MB.
// ---------------------------------------------------------------------------
__global__ __launch_bounds__(512, 6) void yoso_main(
    const unsigned short* __restrict__ qimg, const unsigned short* __restrict__ kimg,
    const unsigned short* __restrict__ vimg, const float* __restrict__ V,
    const float* __restrict__ mask, const float* __restrict__ conv_w,
    float* __restrict__ out) {
  int bid = blockIdx.x;
  int lid = (bid & 7) * 96 + (bid >> 3);   // XCD swizzle (nwg=768=8*96)
  int bh = lid >> 5;
  int b  = bh / NH;
  int h  = bh % NH;
  int qt = lid & 31;
  int s0 = qt * 64;

  __shared__ unsigned short kstage[2][4096];  // 2 x 8KB single-tile buffers

  int tid  = threadIdx.x;
  int wv   = tid >> 6;       // 0..7
  int lane = tid & 63;
  int lq   = lane & 15;
  int quad = lane >> 4;
  int j    = wv & 3;         // q slice (16 rows)
  int tk   = wv >> 2;        // key half within tile

  // Loop-invariant Q fragments for our slice: rows s0 + j*16 + lq.
  uint4 qfrag[2];   // [kk]
  {
    const unsigned short* qtile = qimg + (size_t)(bh * 32 + qt) * TILE_USHORT;
    #pragma unroll
    for (int kk = 0; kk < 2; ++kk)
      qfrag[kk] = *(const uint4*)(qtile + (kk * 4 + j) * 512 + lane * 8);
  }

  float w0 = conv_w[h * 3 + 0], w1 = conv_w[h * 3 + 1], w2 = conv_w[h * 3 + 2];

  floatx4 acc[4];   // [fd]: partial X^T over keys of our tk half
  #pragma unroll
  for (int fd = 0; fd < 4; ++fd) acc[fd] = (floatx4){0.f, 0.f, 0.f, 0.f};

  const unsigned short* kb  = kimg + (size_t)bh * 32 * TILE_USHORT;
  const unsigned short* vbI = vimg + (size_t)bh * 32 * TILE_USHORT;

  const float P0 = 0.3183098862f;
  const float P1 = 0.0530516477f;
  const float P2 = 0.0238732415f;
  const float P3 = 0.0142098402f;
  const float P4 = 0.0096701727f;
  const float P5 = 0.0071212906f;

  // Stage one 8KB K tile: 8 x 1KB pieces, wave wv stages piece wv.
  auto stage_tile = [&](int buf, int kt) {
    gload_lds16(kb + (size_t)kt * TILE_USHORT + wv * 512 + lane * 8,
                &kstage[buf][wv * 512]);
  };

  stage_tile(0, 0);
  __syncthreads();

  #pragma unroll 1
  for (int kt = 0; kt < 32; ++kt) {
    int cur = kt & 1;
    if (kt < 31) stage_tile(cur ^ 1, kt + 1);

    const unsigned short* sb = kstage[cur];

    // --- K fragments for our key half: global ft = tk*2 + fl ---
    uint4 kf[2][2];   // [kk][fl]
    #pragma unroll
    for (int kk = 0; kk < 2; ++kk)
      #pragma unroll
      for (int fl = 0; fl < 2; ++fl)
        kf[kk][fl] = *(const uint4*)(sb + (kk * 4 + tk * 2 + fl) * 512 + lane * 8);

    floatx4 sc[2];   // [fl]: keys t = (tk*2+fl)*16 + quad*4 + r
    #pragma unroll
    for (int fl = 0; fl < 2; ++fl) sc[fl] = (floatx4){0.f, 0.f, 0.f, 0.f};
    #pragma unroll
    for (int kk = 0; kk < 2; ++kk) {
      short8 bq = *(const short8*)&qfrag[kk];
      #pragma unroll
      for (int fl = 0; fl < 2; ++fl)
        sc[fl] = __builtin_amdgcn_mfma_f32_16x16x32_bf16(
            *(const short8*)&kf[kk][fl], bq, sc[fl], 0, 0, 0);
    }

    // --- V fragments for our key half (kk2 = tk): 4KB direct from L2 ---
    const unsigned short* vtile = vbI + (size_t)kt * TILE_USHORT;
    uint4 vf[4];
    #pragma unroll
    for (int fd = 0; fd < 4; ++fd)
      vf[fd] = *(const uint4*)(vtile + (tk * 4 + fd) * 512 + lane * 8);

    // --- transform in place: sc := W = (1/2 + asin(d)/pi)^8 ---
    {
      float2v mxy = mk2(0.f);
      #pragma unroll
      for (int fl = 0; fl < 2; ++fl) {
        float2v* p = (float2v*)&sc[fl];
        mxy = max2(mxy, max2(abs2(p[0]), abs2(p[1])));
      }
      float mx = fmaxf(mxy[0], mxy[1]);
      if (__builtin_expect(__any(mx > 0.82f), 0)) {
        #pragma unroll
        for (int fl = 0; fl < 2; ++fl)
          #pragma unroll
          for (int r2 = 0; r2 < 4; ++r2) {
            float f = yoso_f_exact(sc[fl][r2]);
            float f2 = f * f;
            float f4 = f2 * f2;
            sc[fl][r2] = f4 * f4;
          }
      } else {
        float2v c5 = mk2(P5), c4 = mk2(P4), c3 = mk2(P3), c2 = mk2(P2),
                c1 = mk2(P1), c0 = mk2(P0), hf = mk2(0.5f);
        #pragma unroll
        for (int fl = 0; fl < 2; ++fl) {
          float2v* p = (float2v*)&sc[fl];
          #pragma unroll
          for (int hh = 0; hh < 2; ++hh) {
            float2v d = p[hh];
            float2v y = d * d;
            float2v pp = ((((c5 * y + c4) * y + c3) * y + c2) * y + c1) * y + c0;
            float2v f = pp * d + hf;
            float2v f2 = f * f;
            float2v f4 = f2 * f2;
            p[hh] = f4 * f4;
          }
        }
      }
    }

    // --- MFMA#2: partial X^T += Vm^T · W^T (our kk2 = tk only) ---
    {
      uint4 u;
      u.x = pack_bf16_trunc(sc[0][0], sc[0][1]);
      u.y = pack_bf16_trunc(sc[0][2], sc[0][3]);
      u.z = pack_bf16_trunc(sc[1][0], sc[1][1]);
      u.w = pack_bf16_trunc(sc[1][2], sc[1][3]);
      short8 bw = *(short8*)&u;
      #pragma unroll
      for (int fd = 0; fd < 4; ++fd)
        acc[fd] = __builtin_amdgcn_mfma_f32_16x16x32_bf16(
            *(const short8*)&vf[fd], bw, acc[fd], 0, 0, 0);
    }

    __syncthreads();   // stage(kt+1) complete; buf free for kt+2 writes
  }

  // --- 1-step reduction over tk via kstage (4 x 4KB slices, exact fit) ---
  // Slice j layout: xch[j*1024 + col*16 + lq], col = fd*16 + quad*4 + r2.
  float* xch = (float*)&kstage[0][0];
  if (tk == 1) {
    float* wr = xch + (j << 10);
    #pragma unroll
    for (int fd = 0; fd < 4; ++fd)
      #pragma unroll
      for (int r2 = 0; r2 < 4; ++r2)
        wr[(fd * 16 + quad * 4 + r2) * 16 + lq] = acc[fd][r2];
  }
  __syncthreads();
  if (tk == 0) {
    const float* rd = xch + (j << 10);
    #pragma unroll
    for (int fd = 0; fd < 4; ++fd)
      #pragma unroll
      for (int r2 = 0; r2 < 4; ++r2)
        acc[fd][r2] += rd[(fd * 16 + quad * 4 + r2) * 16 + lq];

    // --- epilogue: q = s0 + j*16 + lq ---
    int s = s0 + j * 16 + lq;
    float qm  = mask[b * NS + s];
    float qm0 = (s > 0) ? mask[b * NS + s - 1] : 0.f;
    float qm2 = (s < NS - 1) ? mask[b * NS + s + 1] : 0.f;
    float ssum = 0.f;
    #pragma unroll
    for (int fd = 0; fd < 4; ++fd)
      #pragma unroll
      for (int r2 = 0; r2 < 4; ++r2) {
        float x = acc[fd][r2] * qm;
        acc[fd][r2] = x;
        ssum += x * x;
      }
    ssum += __shfl_xor(ssum, 16, 64);
    ssum += __shfl_xor(ssum, 32, 64);
    float rn = 1.0f / fmaxf(sqrtf(ssum), 1e-12f);

    const float* vfull = V + ((size_t)bh * NS + s) * ND;
    #pragma unroll
    for (int fd = 0; fd < 4; ++fd) {
      int d = fd * 16 + quad * 4;
      float4 vc1 = *(const float4*)(vfull + d);
      float4 cv;
      cv.x = w1 * vc1.x * qm; cv.y = w1 * vc1.y * qm;
      cv.z = w1 * vc1.z * qm; cv.w = w1 * vc1.w * qm;
      if (s > 0) {
        float4 vc0 = *(const float4*)(vfull - ND + d);
        cv.x += w0 * vc0.x * qm0; cv.y += w0 * vc0.y * qm0;
        cv.z += w0 * vc0.z * qm0; cv.w += w0 * vc0.w * qm0;
      }
      if (s < NS - 1) {
        float4 vc2 = *(const float4*)(vfull + ND + d);
        cv.x += w2 * vc2.x * qm2; cv.y += w2 * vc2.y * qm2;
        cv.z += w2 * vc2.z * qm2; cv.w += w2 * vc2.w * qm2;
      }
      float4 o;
      o.x = acc[fd][0] * rn + cv.x;
      o.y = acc[fd][1] * rn + cv.y;
      o.z = acc[fd][2] * rn + cv.z;
      o.w = acc[fd][3] * rn + cv.w;
      *(float4*)(out + ((size_t)bh * NS + s) * ND + d) = o;
    }
  }
}

// ---------------------------------------------------------------------------
extern "C" void kernel_launch(void* const* d_in, const int* in_sizes, int n_in,
                              void* d_out, int out_size, void* d_ws, size_t ws_size,
                              hipStream_t stream) {
  const float* Q      = (const float*)d_in[0];
  const float* K      = (const float*)d_in[1];
  const float* V      = (const float*)d_in[2];
  const float* mask   = (const float*)d_in[3];
  const float* conv_w = (const float*)d_in[4];
  float* out = (float*)d_out;

  const size_t seg = (size_t)NBH * NS * ND * sizeof(unsigned short);  // 6.29 MB
  unsigned short* qimg = (unsigned short*)d_ws;
  unsigned short* kimg = (unsigned short*)((char*)d_ws + seg);
  unsigned short* vimg = (unsigned short*)((char*)d_ws + 2 * seg);

  prep_all<<<QK_TILE_BLOCKS + V_BLOCKS, 256, 0, stream>>>(Q, K, V, mask, qimg, kimg, vimg);
  yoso_main<<<NBH * 32, 512, 0, stream>>>(qimg, kimg, vimg, V, mask, conv_w, out);
}